// Round 2
// baseline (21322.931 us; speedup 1.0000x reference)
//
#include <hip/hip_runtime.h>
#include <math.h>

// Problem dims
#define BB 64
#define TT 512
#define DD 256
#define HH 1024
#define GG 4096  // 4*H
#define NBLK 256 // persistent grid size (1 block per CU)

typedef __bf16 bf16x8 __attribute__((ext_vector_type(8)));
typedef float floatx4 __attribute__((ext_vector_type(4)));

__device__ __forceinline__ float fast_sigmoid(float x) {
    return __builtin_amdgcn_rcpf(1.0f + __expf(-x));
}
__device__ __forceinline__ float fast_tanh(float x) {
    // 1 - 2/(1+e^{2x}); exp->inf and exp->0 limits give +/-1 correctly
    return 1.0f - 2.0f * __builtin_amdgcn_rcpf(1.0f + __expf(2.0f * x));
}

// ---------------- fp32 -> bf16 conversion (weights) ----------------
__global__ void cvt_bf16_kernel(const float* __restrict__ src,
                                __bf16* __restrict__ dst, int n) {
    int i = (blockIdx.x * blockDim.x + threadIdx.x) * 8;
    if (i >= n) return;
    float4 a = *(const float4*)(src + i);
    float4 b = *(const float4*)(src + i + 4);
    bf16x8 v;
    v[0] = (__bf16)a.x; v[1] = (__bf16)a.y; v[2] = (__bf16)a.z; v[3] = (__bf16)a.w;
    v[4] = (__bf16)b.x; v[5] = (__bf16)b.y; v[6] = (__bf16)b.z; v[7] = (__bf16)b.w;
    *(bf16x8*)(dst + i) = v;
}

// ---------------- init: combined bias, zero barrier counters ----------------
__global__ void init_misc_kernel(const float* __restrict__ bx,
                                 const float* __restrict__ bh,
                                 float* __restrict__ bc,
                                 int* __restrict__ bar) {
    int i = blockIdx.x * blockDim.x + threadIdx.x;
    if (i < GG) bc[i] = bx[i] + bh[i];
    if (i < 256) bar[i] = 0;  // 8 counters, stride 32 ints (128B apart)
}

// ---------------- persistent LSTM: all 512 timesteps in one kernel ----------
// grid: 256 blocks (j-tile of 4), 256 threads (4 waves). Weights live in LDS
// for the whole sequence; cell state lives in one register per thread;
// steps are separated by a device-scope multi-counter grid barrier.
__global__ __launch_bounds__(256) void lstm_persist_kernel(
    const float* __restrict__ x,      // (B,T,D) fp32
    const __bf16* __restrict__ Wxb,   // (4096,256) bf16
    const __bf16* __restrict__ Whb,   // (4096,1024) bf16
    const float* __restrict__ bc,     // (4096) combined bias
    float* __restrict__ hs,           // (B,T,H) fp32 raw h (d_out hidden region)
    __bf16* __restrict__ hping,       // 2 x (B*H) bf16 ping-pong h
    int* __restrict__ bar) {          // 8 counters at bar[0,32,...,224]
    // 16 gathered gate rows x 1280 K, +8 pad per row for LDS bank spread
    __shared__ __bf16 W_s[16][1288];
    __shared__ float gate_s[64][17];

    const int tid = threadIdx.x;
    const int j0 = blockIdx.x * 4;

    // Stage [Wx | Wh] rows for the 16 packed gate rows, ONCE.
    for (int ch = tid; ch < 2560; ch += 256) {
        int r = ch / 160;
        int pos = ch - r * 160;
        int k = pos * 8;
        int gate = r >> 2;
        int jj_ = r & 3;
        int gr = gate * HH + j0 + jj_;
        const __bf16* src = (k < DD) ? (Wxb + (size_t)gr * DD + k)
                                     : (Whb + (size_t)gr * HH + (k - DD));
        *(uint4*)(&W_s[r][k]) = *(const uint4*)src;
    }
    __syncthreads();

    const int wave = tid >> 6;
    const int lane = tid & 63;
    const int ln = lane & 15;   // A row (b within wave tile) AND B row (packed gate)
    const int q = lane >> 4;    // k-quad
    const int brow = wave * 16 + ln;

    // epilogue mapping: one (b, j) pair per thread
    const int b2 = tid >> 2;
    const int jj = tid & 3;
    const int j = j0 + jj;
    const float bci = bc[j];
    const float bcf = bc[HH + j];
    const float bcg = bc[2 * HH + j];
    const float bco = bc[3 * HH + j];
    float creg = 0.0f;  // cell state lives here for all 512 steps

    const float* xbase = x + (size_t)brow * TT * DD;
    float* hs_pt = hs + (size_t)b2 * TT * HH + j;

    // x-part prefetch for t=0
    floatx4 acc_x = {0.f, 0.f, 0.f, 0.f};
    {
        const float* xrow = xbase;  // t = 0
#pragma unroll
        for (int k0 = 0; k0 < DD; k0 += 32) {
            int ka = k0 + q * 8;
            float4 f0 = *(const float4*)(xrow + ka);
            float4 f1 = *(const float4*)(xrow + ka + 4);
            bf16x8 av;
            av[0] = (__bf16)f0.x; av[1] = (__bf16)f0.y;
            av[2] = (__bf16)f0.z; av[3] = (__bf16)f0.w;
            av[4] = (__bf16)f1.x; av[5] = (__bf16)f1.y;
            av[6] = (__bf16)f1.z; av[7] = (__bf16)f1.w;
            bf16x8 bv = *(const bf16x8*)(&W_s[ln][ka]);
            acc_x = __builtin_amdgcn_mfma_f32_16x16x32_bf16(av, bv, acc_x, 0, 0, 0);
        }
    }

    int target = 0;
    for (int t = 0; t < TT; ++t) {
        floatx4 acc = acc_x;

        // h part: K = 256..1279, h_{t-1} from bf16 ping-pong buffer
        if (t > 0) {
            const __bf16* hrow =
                hping + (size_t)((t - 1) & 1) * (BB * HH) + (size_t)brow * HH;
#pragma unroll 8
            for (int k0 = 0; k0 < HH; k0 += 32) {
                int ka = k0 + q * 8;
                bf16x8 av = *(const bf16x8*)(hrow + ka);
                bf16x8 bv = *(const bf16x8*)(&W_s[ln][DD + ka]);
                acc = __builtin_amdgcn_mfma_f32_16x16x32_bf16(av, bv, acc, 0, 0, 0);
            }
        }

        // C[row=(q*4+r)][col=ln] -> LDS so each thread can gather its 4 gates
#pragma unroll
        for (int r = 0; r < 4; ++r)
            gate_s[wave * 16 + q * 4 + r][ln] = acc[r];
        __syncthreads();

        float iv = fast_sigmoid(gate_s[b2][jj] + bci);
        float fv = fast_sigmoid(gate_s[b2][4 + jj] + bcf);
        float gv = fast_sigmoid(gate_s[b2][8 + jj] + bcg);  // ref sigmoids cell gate
        float ov = fast_sigmoid(gate_s[b2][12 + jj] + bco);
        creg = creg * fv + iv * gv;
        float hh = ov * fast_tanh(creg);
        hs_pt[(size_t)t * HH] = hh;                                       // raw h
        hping[(size_t)(t & 1) * (BB * HH) + b2 * HH + j] = (__bf16)hh;    // next step

        // x-part prefetch for t+1 (independent of h; hides behind barrier)
        if (t + 1 < TT) {
            const float* xrow = xbase + (size_t)(t + 1) * DD;
            floatx4 ax = {0.f, 0.f, 0.f, 0.f};
#pragma unroll
            for (int k0 = 0; k0 < DD; k0 += 32) {
                int ka = k0 + q * 8;
                float4 f0 = *(const float4*)(xrow + ka);
                float4 f1 = *(const float4*)(xrow + ka + 4);
                bf16x8 av;
                av[0] = (__bf16)f0.x; av[1] = (__bf16)f0.y;
                av[2] = (__bf16)f0.z; av[3] = (__bf16)f0.w;
                av[4] = (__bf16)f1.x; av[5] = (__bf16)f1.y;
                av[6] = (__bf16)f1.z; av[7] = (__bf16)f1.w;
                bf16x8 bv = *(const bf16x8*)(&W_s[ln][ka]);
                ax = __builtin_amdgcn_mfma_f32_16x16x32_bf16(av, bv, ax, 0, 0, 0);
            }
            acc_x = ax;

            // ---- grid barrier (skip after last step) ----
            target += NBLK;
            __syncthreads();  // all threads' hping writes done
            if (tid == 0) {
                __hip_atomic_fetch_add(&bar[(blockIdx.x & 7) * 32], 1,
                                       __ATOMIC_RELEASE, __HIP_MEMORY_SCOPE_AGENT);
                int sum;
                do {
                    sum = 0;
#pragma unroll
                    for (int i = 0; i < 8; ++i)
                        sum += __hip_atomic_load(&bar[i * 32], __ATOMIC_ACQUIRE,
                                                 __HIP_MEMORY_SCOPE_AGENT);
                } while (sum < target);
            }
            __syncthreads();  // releases whole block past barrier
        }
    }
}

// ---------------- output head: out = hs @ Wout^T + bout ----------------
__global__ __launch_bounds__(256) void out_gemm_kernel(
    const float* __restrict__ hs,    // (B*T, H) raw fp32
    const __bf16* __restrict__ Wob,  // (D, H) bf16
    const float* __restrict__ bout,  // (D)
    float* __restrict__ out) {       // (B*T, D)
    __shared__ __bf16 Wout_s[16][1032];
    const int tid = threadIdx.x;
    const int d0 = blockIdx.x * 16;
    const int row0 = blockIdx.y * 64;

    for (int ch = tid; ch < 2048; ch += 256) {
        int r = ch >> 7;
        int k = (ch & 127) * 8;
        *(uint4*)(&Wout_s[r][k]) = *(const uint4*)(Wob + (size_t)(d0 + r) * HH + k);
    }
    __syncthreads();

    const int wave = tid >> 6;
    const int lane = tid & 63;
    const int ln = lane & 15;
    const int q = lane >> 4;
    const int row = row0 + wave * 16 + ln;

    const float* arow = hs + (size_t)row * HH;
    floatx4 acc = {0.f, 0.f, 0.f, 0.f};
#pragma unroll 8
    for (int k0 = 0; k0 < HH; k0 += 32) {
        int ka = k0 + q * 8;
        float4 f0 = *(const float4*)(arow + ka);
        float4 f1 = *(const float4*)(arow + ka + 4);
        bf16x8 av;
        av[0] = (__bf16)f0.x; av[1] = (__bf16)f0.y;
        av[2] = (__bf16)f0.z; av[3] = (__bf16)f0.w;
        av[4] = (__bf16)f1.x; av[5] = (__bf16)f1.y;
        av[6] = (__bf16)f1.z; av[7] = (__bf16)f1.w;
        bf16x8 bv = *(const bf16x8*)(&Wout_s[ln][ka]);
        acc = __builtin_amdgcn_mfma_f32_16x16x32_bf16(av, bv, acc, 0, 0, 0);
    }
    float bo = bout[d0 + ln];
    const int orow0 = row0 + wave * 16 + q * 4;
#pragma unroll
    for (int r = 0; r < 4; ++r)
        out[(size_t)(orow0 + r) * DD + d0 + ln] = acc[r] + bo;
}

// ---------------- in-place tanh over hidden region ----------------
__global__ void tanh_inplace_kernel(float* __restrict__ p, size_t n) {
    size_t i = ((size_t)blockIdx.x * blockDim.x + threadIdx.x) * 4;
    size_t stride = (size_t)gridDim.x * blockDim.x * 4;
    for (; i < n; i += stride) {
        float4 v = *(float4*)(p + i);
        v.x = fast_tanh(v.x); v.y = fast_tanh(v.y);
        v.z = fast_tanh(v.z); v.w = fast_tanh(v.w);
        *(float4*)(p + i) = v;
    }
}

extern "C" void kernel_launch(void* const* d_in, const int* in_sizes, int n_in,
                              void* d_out, int out_size, void* d_ws, size_t ws_size,
                              hipStream_t stream) {
    const float* x    = (const float*)d_in[0];  // (B,T,D)
    const float* Wx   = (const float*)d_in[1];  // (4H,D)
    const float* bx   = (const float*)d_in[2];  // (4H)
    const float* Wh   = (const float*)d_in[3];  // (4H,H)
    const float* bh   = (const float*)d_in[4];  // (4H)
    const float* Wout = (const float*)d_in[5];  // (D,H)
    const float* bout = (const float*)d_in[6];  // (D)

    float* out = (float*)d_out;                        // (B,T,D)
    float* hidden = out + (size_t)BB * TT * DD;        // (B,T,H): raw h, then tanh'd

    // workspace layout (16B aligned), ~11.3 MB total
    char* ws = (char*)d_ws;
    __bf16* Wxb   = (__bf16*)(ws);                      // 2 MB   (4096x256)
    __bf16* Whb   = (__bf16*)(ws + 2097152);            // 8 MB   (4096x1024)
    __bf16* Wob   = (__bf16*)(ws + 10485760);           // 512 KB (256x1024)
    float*  bc    = (float*)(ws + 11010048);            // 16 KB
    __bf16* hping = (__bf16*)(ws + 11026432);           // 256 KB (2 x B*H)
    int*    bar   = (int*)(ws + 11288576);              // 1 KB   (8 counters, padded)

    // weight conversions + init
    cvt_bf16_kernel<<<(GG * DD / 8 + 255) / 256, 256, 0, stream>>>(Wx, Wxb, GG * DD);
    cvt_bf16_kernel<<<(GG * HH / 8 + 255) / 256, 256, 0, stream>>>(Wh, Whb, GG * HH);
    cvt_bf16_kernel<<<(DD * HH / 8 + 255) / 256, 256, 0, stream>>>(Wout, Wob, DD * HH);
    init_misc_kernel<<<(GG + 255) / 256, 256, 0, stream>>>(bx, bh, bc, bar);

    // whole recurrence in ONE persistent kernel (grid barrier between steps)
    lstm_persist_kernel<<<NBLK, 256, 0, stream>>>(x, Wxb, Whb, bc, hidden, hping, bar);

    // output head, then tanh the hidden region in place
    out_gemm_kernel<<<dim3(DD / 16, (BB * TT) / 64), 256, 0, stream>>>(
        hidden, Wob, bout, out);
    tanh_inplace_kernel<<<2048, 256, 0, stream>>>(hidden, (size_t)BB * TT * HH);
}

// Round 3
// 7020.145 us; speedup vs baseline: 3.0374x; 3.0374x over previous
//
#include <hip/hip_runtime.h>
#include <math.h>

// Problem dims
#define BB 64
#define TT 512
#define DD 256
#define HH 1024
#define GG 4096   // 4*H
#define NBLK 256  // persistent grid size (1 block per CU)
#define JT 8      // j-tile per block (32 gate rows), batch-half = 32

typedef __bf16 bf16x8 __attribute__((ext_vector_type(8)));
typedef float floatx4 __attribute__((ext_vector_type(4)));

__device__ __forceinline__ float fast_sigmoid(float x) {
    return __builtin_amdgcn_rcpf(1.0f + __expf(-x));
}
__device__ __forceinline__ float fast_tanh(float x) {
    return 1.0f - 2.0f * __builtin_amdgcn_rcpf(1.0f + __expf(2.0f * x));
}

// ---------------- fp32 -> bf16 conversion (weights) ----------------
__global__ void cvt_bf16_kernel(const float* __restrict__ src,
                                __bf16* __restrict__ dst, int n) {
    int i = (blockIdx.x * blockDim.x + threadIdx.x) * 8;
    if (i >= n) return;
    float4 a = *(const float4*)(src + i);
    float4 b = *(const float4*)(src + i + 4);
    bf16x8 v;
    v[0] = (__bf16)a.x; v[1] = (__bf16)a.y; v[2] = (__bf16)a.z; v[3] = (__bf16)a.w;
    v[4] = (__bf16)b.x; v[5] = (__bf16)b.y; v[6] = (__bf16)b.z; v[7] = (__bf16)b.w;
    *(bf16x8*)(dst + i) = v;
}

// ---------------- init: combined bias, zero barrier counters ----------------
__global__ void init_misc_kernel(const float* __restrict__ bx,
                                 const float* __restrict__ bh,
                                 float* __restrict__ bc,
                                 int* __restrict__ bar) {
    int i = blockIdx.x * blockDim.x + threadIdx.x;
    if (i < GG) bc[i] = bx[i] + bh[i];
    if (i < 512) bar[i] = 0;  // group counters @ g*32, root @ 256, flag @ 288
}

// ---------------- grid barrier: 2-level arrival + epoch flag --------------
// ONE release-RMW per block per step; RELAXED spin; ONE acquire fence.
__device__ __forceinline__ void grid_bar(int* __restrict__ bar, int t, int tid,
                                         int bid) {
    __syncthreads();  // all this block's stores issued & drained (vmcnt0)
    if (tid == 0) {
        int g = bid & 7;
        int old = __hip_atomic_fetch_add(&bar[g * 32], 1, __ATOMIC_RELEASE,
                                         __HIP_MEMORY_SCOPE_AGENT);
        if (old == 32 * (t + 1) - 1) {  // last arriver of this group
            int r = __hip_atomic_fetch_add(&bar[256], 1, __ATOMIC_ACQ_REL,
                                           __HIP_MEMORY_SCOPE_AGENT);
            if (r == 8 * (t + 1) - 1) {  // last group overall -> publish epoch
                __hip_atomic_store(&bar[288], t + 1, __ATOMIC_RELEASE,
                                   __HIP_MEMORY_SCOPE_AGENT);
            }
        }
        while (__hip_atomic_load(&bar[288], __ATOMIC_RELAXED,
                                 __HIP_MEMORY_SCOPE_AGENT) < t + 1) {
            __builtin_amdgcn_s_sleep(1);
        }
        __builtin_amdgcn_fence(__ATOMIC_ACQUIRE, "agent");
    }
    __syncthreads();
}

// ---------------- persistent LSTM: all 512 timesteps in one kernel ----------
// 256 blocks = 128 j-tiles (8 j each) x 2 batch-halves (32 b each).
// Weights for the block's 32 gate rows live in LDS (80 KB, swizzled so every
// wave B-fragment read is ds_read_b128 at base + lane*16B: conflict-free).
// Wave w = (wb = w>>1 batch 16-group, wg = w&1 gate 16-group).
__global__ __launch_bounds__(256) void lstm_persist_kernel(
    const float* __restrict__ x,      // (B,T,D) fp32
    const __bf16* __restrict__ Wxb,   // (4096,256) bf16
    const __bf16* __restrict__ Whb,   // (4096,1024) bf16
    const float* __restrict__ bc,     // (4096) combined bias
    float* __restrict__ hs,           // (B,T,H) fp32 raw h (d_out hidden region)
    __bf16* __restrict__ hping,       // 2 x (B*H) bf16 ping-pong h
    int* __restrict__ bar) {
    // swizzled weights: chunk (row r, c) at idx16 = (c>>2)*128+(r>>4)*64+(c&3)*16+(r&15)
    __shared__ bf16x8 W_s[32 * 160];     // 80 KB
    __shared__ float gate_s[32][33];     // C round-trip for epilogue

    const int tid = threadIdx.x;
    const int bid = blockIdx.x;
    const int j0 = (bid >> 1) * JT;
    const int b0 = (bid & 1) * 32;

    // Stage the 32 gate rows (r = gate*8 + jj) once, swizzled.
    for (int ch = tid; ch < 32 * 160; ch += 256) {
        int r = ch / 160;
        int c = ch - r * 160;
        int k = c * 8;
        int gate = r >> 3;
        int jj_ = r & 7;
        int gr = gate * HH + j0 + jj_;
        const __bf16* src = (k < DD) ? (Wxb + (size_t)gr * DD + k)
                                     : (Whb + (size_t)gr * HH + (k - DD));
        int idx16 = (c >> 2) * 128 + (r >> 4) * 64 + (c & 3) * 16 + (r & 15);
        *(uint4*)&W_s[idx16] = *(const uint4*)src;
    }
    __syncthreads();

    const int wave = tid >> 6;
    const int lane = tid & 63;
    const int wb = wave >> 1;  // batch 16-group within the 32-half
    const int wg = wave & 1;   // gate-col 16-group within the 32 rows
    const int ln = lane & 15;
    const int q = lane >> 4;
    const int abatch = b0 + wb * 16 + ln;  // A-fragment source row (global batch)

    // epilogue mapping: thread -> (local batch b2, jj)
    const int b2 = tid >> 3;        // 0..31
    const int jj = tid & 7;         // 0..7
    const int j = j0 + jj;
    const int gb = b0 + b2;         // global batch
    const float bci = bc[j];
    const float bcf = bc[HH + j];
    const float bcg = bc[2 * HH + j];
    const float bco = bc[3 * HH + j];
    float creg = 0.0f;

    const float* xbase = x + (size_t)abatch * TT * DD;
    float* hs_pt = hs + ((size_t)gb * TT) * HH + j;
    const bf16x8* Wv = W_s + wg * 64 + lane;  // + I*128 per k-iter

    // x-part prefetch for t=0
    floatx4 acc_x = {0.f, 0.f, 0.f, 0.f};
#pragma unroll
    for (int I = 0; I < 8; ++I) {
        int ka = I * 32 + q * 8;
        float4 f0 = *(const float4*)(xbase + ka);
        float4 f1 = *(const float4*)(xbase + ka + 4);
        bf16x8 av;
        av[0] = (__bf16)f0.x; av[1] = (__bf16)f0.y;
        av[2] = (__bf16)f0.z; av[3] = (__bf16)f0.w;
        av[4] = (__bf16)f1.x; av[5] = (__bf16)f1.y;
        av[6] = (__bf16)f1.z; av[7] = (__bf16)f1.w;
        acc_x = __builtin_amdgcn_mfma_f32_16x16x32_bf16(av, Wv[I * 128], acc_x,
                                                        0, 0, 0);
    }

    for (int t = 0; t < TT; ++t) {
        floatx4 acc = acc_x;

        // h part: K = 256..1279, h_{t-1} from bf16 ping-pong buffer
        if (t > 0) {
            const __bf16* hrow =
                hping + (size_t)((t - 1) & 1) * (BB * HH) + (size_t)abatch * HH;
#pragma unroll 8
            for (int I = 8; I < 40; ++I) {
                int ka = (I - 8) * 32 + q * 8;
                bf16x8 av = *(const bf16x8*)(hrow + ka);
                acc = __builtin_amdgcn_mfma_f32_16x16x32_bf16(av, Wv[I * 128],
                                                              acc, 0, 0, 0);
            }
        }

        // C[lb = wb*16 + q*4 + r][n = wg*16 + ln] -> LDS
#pragma unroll
        for (int r = 0; r < 4; ++r)
            gate_s[wb * 16 + q * 4 + r][wg * 16 + ln] = acc[r];
        __syncthreads();

        float iv = fast_sigmoid(gate_s[b2][jj] + bci);
        float fv = fast_sigmoid(gate_s[b2][8 + jj] + bcf);
        float gv = fast_sigmoid(gate_s[b2][16 + jj] + bcg);  // ref sigmoids g
        float ov = fast_sigmoid(gate_s[b2][24 + jj] + bco);
        creg = creg * fv + iv * gv;
        float hh = ov * fast_tanh(creg);
        hs_pt[(size_t)t * HH] = hh;
        hping[(size_t)(t & 1) * (BB * HH) + (size_t)gb * HH + j] = (__bf16)hh;

        if (t + 1 < TT) {
            // x-part prefetch for t+1 (h-independent; overlaps barrier wait)
            const float* xrow = xbase + (size_t)(t + 1) * DD;
            floatx4 ax = {0.f, 0.f, 0.f, 0.f};
#pragma unroll
            for (int I = 0; I < 8; ++I) {
                int ka = I * 32 + q * 8;
                float4 f0 = *(const float4*)(xrow + ka);
                float4 f1 = *(const float4*)(xrow + ka + 4);
                bf16x8 av;
                av[0] = (__bf16)f0.x; av[1] = (__bf16)f0.y;
                av[2] = (__bf16)f0.z; av[3] = (__bf16)f0.w;
                av[4] = (__bf16)f1.x; av[5] = (__bf16)f1.y;
                av[6] = (__bf16)f1.z; av[7] = (__bf16)f1.w;
                ax = __builtin_amdgcn_mfma_f32_16x16x32_bf16(av, Wv[I * 128],
                                                             ax, 0, 0, 0);
            }
            acc_x = ax;

            grid_bar(bar, t, tid, bid);
        }
    }
}

// ---------------- output head: out = hs @ Wout^T + bout ----------------
__global__ __launch_bounds__(256) void out_gemm_kernel(
    const float* __restrict__ hs,    // (B*T, H) raw fp32
    const __bf16* __restrict__ Wob,  // (D, H) bf16
    const float* __restrict__ bout,  // (D)
    float* __restrict__ out) {       // (B*T, D)
    __shared__ __bf16 Wout_s[16][1032];
    const int tid = threadIdx.x;
    const int d0 = blockIdx.x * 16;
    const int row0 = blockIdx.y * 64;

    for (int ch = tid; ch < 2048; ch += 256) {
        int r = ch >> 7;
        int k = (ch & 127) * 8;
        *(uint4*)(&Wout_s[r][k]) = *(const uint4*)(Wob + (size_t)(d0 + r) * HH + k);
    }
    __syncthreads();

    const int wave = tid >> 6;
    const int lane = tid & 63;
    const int ln = lane & 15;
    const int q = lane >> 4;
    const int row = row0 + wave * 16 + ln;

    const float* arow = hs + (size_t)row * HH;
    floatx4 acc = {0.f, 0.f, 0.f, 0.f};
#pragma unroll 8
    for (int k0 = 0; k0 < HH; k0 += 32) {
        int ka = k0 + q * 8;
        float4 f0 = *(const float4*)(arow + ka);
        float4 f1 = *(const float4*)(arow + ka + 4);
        bf16x8 av;
        av[0] = (__bf16)f0.x; av[1] = (__bf16)f0.y;
        av[2] = (__bf16)f0.z; av[3] = (__bf16)f0.w;
        av[4] = (__bf16)f1.x; av[5] = (__bf16)f1.y;
        av[6] = (__bf16)f1.z; av[7] = (__bf16)f1.w;
        bf16x8 bv = *(const bf16x8*)(&Wout_s[ln][ka]);
        acc = __builtin_amdgcn_mfma_f32_16x16x32_bf16(av, bv, acc, 0, 0, 0);
    }
    float bo = bout[d0 + ln];
    const int orow0 = row0 + wave * 16 + q * 4;
#pragma unroll
    for (int r = 0; r < 4; ++r)
        out[(size_t)(orow0 + r) * DD + d0 + ln] = acc[r] + bo;
}

// ---------------- in-place tanh over hidden region ----------------
__global__ void tanh_inplace_kernel(float* __restrict__ p, size_t n) {
    size_t i = ((size_t)blockIdx.x * blockDim.x + threadIdx.x) * 4;
    size_t stride = (size_t)gridDim.x * blockDim.x * 4;
    for (; i < n; i += stride) {
        float4 v = *(float4*)(p + i);
        v.x = fast_tanh(v.x); v.y = fast_tanh(v.y);
        v.z = fast_tanh(v.z); v.w = fast_tanh(v.w);
        *(float4*)(p + i) = v;
    }
}

extern "C" void kernel_launch(void* const* d_in, const int* in_sizes, int n_in,
                              void* d_out, int out_size, void* d_ws, size_t ws_size,
                              hipStream_t stream) {
    const float* x    = (const float*)d_in[0];  // (B,T,D)
    const float* Wx   = (const float*)d_in[1];  // (4H,D)
    const float* bx   = (const float*)d_in[2];  // (4H)
    const float* Wh   = (const float*)d_in[3];  // (4H,H)
    const float* bh   = (const float*)d_in[4];  // (4H)
    const float* Wout = (const float*)d_in[5];  // (D,H)
    const float* bout = (const float*)d_in[6];  // (D)

    float* out = (float*)d_out;                        // (B,T,D)
    float* hidden = out + (size_t)BB * TT * DD;        // (B,T,H): raw h, then tanh'd

    // workspace layout (16B aligned), ~11.3 MB total
    char* ws = (char*)d_ws;
    __bf16* Wxb   = (__bf16*)(ws);                      // 2 MB   (4096x256)
    __bf16* Whb   = (__bf16*)(ws + 2097152);            // 8 MB   (4096x1024)
    __bf16* Wob   = (__bf16*)(ws + 10485760);           // 512 KB (256x1024)
    float*  bc    = (float*)(ws + 11010048);            // 16 KB
    __bf16* hping = (__bf16*)(ws + 11026432);           // 256 KB (2 x B*H)
    int*    bar   = (int*)(ws + 11288576);              // 2 KB

    // weight conversions + init
    cvt_bf16_kernel<<<(GG * DD / 8 + 255) / 256, 256, 0, stream>>>(Wx, Wxb, GG * DD);
    cvt_bf16_kernel<<<(GG * HH / 8 + 255) / 256, 256, 0, stream>>>(Wh, Whb, GG * HH);
    cvt_bf16_kernel<<<(DD * HH / 8 + 255) / 256, 256, 0, stream>>>(Wout, Wob, DD * HH);
    init_misc_kernel<<<(GG + 255) / 256, 256, 0, stream>>>(bx, bh, bc, bar);

    // whole recurrence in ONE persistent kernel (grid barrier between steps)
    lstm_persist_kernel<<<NBLK, 256, 0, stream>>>(x, Wxb, Whb, bc, hidden, hping, bar);

    // output head, then tanh the hidden region in place
    out_gemm_kernel<<<dim3(DD / 16, (BB * TT) / 64), 256, 0, stream>>>(
        hidden, Wob, bout, out);
    tanh_inplace_kernel<<<2048, 256, 0, stream>>>(hidden, (size_t)BB * TT * HH);
}